// Round 3
// baseline (16690.155 us; speedup 1.0000x reference)
//
#include <hip/hip_runtime.h>
#include <hip/hip_bf16.h>

#define T_LEN 512
#define B_SZ  64
#define D_SZ  1024

typedef __attribute__((ext_vector_type(8))) short  short8;   // 8 bf16
typedef __attribute__((ext_vector_type(4))) float  f32x4;
typedef __attribute__((ext_vector_type(4))) unsigned short ushort4v;

__device__ __forceinline__ float bf2f(unsigned short u) {
    unsigned int x = ((unsigned int)u) << 16;
    return __uint_as_float(x);
}
__device__ __forceinline__ unsigned short f2bf(float f) {
    unsigned int x = __float_as_uint(f);
    unsigned int r = x + 0x7FFFu + ((x >> 16) & 1u);   // round-to-nearest-even
    return (unsigned short)(r >> 16);
}
// split via local temps (vector elements can't bind to references)
__device__ __forceinline__ void split2p(float f, unsigned short* hi, unsigned short* lo) {
    unsigned short h = f2bf(f);
    *hi = h;
    *lo = f2bf(f - bf2f(h));
}

// ---------------------------------------------------------------------------
// init: zero the per-batch-group counters (re-zeroed every launch so graph
// replays are deterministic)
// ---------------------------------------------------------------------------
__global__ void init_kernel(int* cnt) {
    if (threadIdx.x < 8) cnt[threadIdx.x] = 0;
}

// ---------------------------------------------------------------------------
// Kernel B: xproj[t,b,:] = x[t,b,:] @ W_ih^T + b_ih   (fp32 out)
// Split-precision: A,B -> (hi,lo) bf16; acc += Ah*Bh + Al*Bh + Ah*Bl.
// M = T*B = 32768, N = D = 1024, K = D = 1024; 128x128 tile, BK=32, 4 waves.
// ---------------------------------------------------------------------------
#define BM 128
#define BN 128
#define BK 32
#define ASTR (BK + 8)   // 40 bf16 rows -> 80 B stride, spreads banks

__global__ __launch_bounds__(256) void xproj_kernel(
    const float* __restrict__ x, const float* __restrict__ Wih,
    const float* __restrict__ bih, float* __restrict__ xp)
{
    __shared__ unsigned short Ah[BM][ASTR];
    __shared__ unsigned short Al[BM][ASTR];
    __shared__ unsigned short Bh[BN][ASTR];
    __shared__ unsigned short Bl[BN][ASTR];

    const int nblk = D_SZ / BN;                 // 8
    const int bm = blockIdx.x / nblk;
    const int bn = blockIdx.x % nblk;
    const int m0 = bm * BM, n0 = bn * BN;
    const int tid  = threadIdx.x;
    const int lane = tid & 63, wave = tid >> 6;
    const int wm = wave >> 1, wn = wave & 1;

    f32x4 acc[4][4];
#pragma unroll
    for (int i = 0; i < 4; i++)
#pragma unroll
        for (int j = 0; j < 4; j++) acc[i][j] = (f32x4)0.0f;

    const int ar = lane & 15;
    const int kb = (lane >> 4) << 3;            // 0,8,16,24

    for (int k0 = 0; k0 < D_SZ; k0 += BK) {
#pragma unroll
        for (int i = 0; i < 4; i++) {
            int f4  = tid + i * 256;            // 0..1023
            int row = f4 >> 3;
            int c4  = (f4 & 7) << 2;
            f32x4 va = *reinterpret_cast<const f32x4*>(x   + (size_t)(m0 + row) * D_SZ + k0 + c4);
            f32x4 vb = *reinterpret_cast<const f32x4*>(Wih + (size_t)(n0 + row) * D_SZ + k0 + c4);
            ushort4v pah, pal, pbh, pbl;
#pragma unroll
            for (int e = 0; e < 4; e++) {
                unsigned short h_, l_;
                split2p(va[e], &h_, &l_); pah[e] = h_; pal[e] = l_;
                split2p(vb[e], &h_, &l_); pbh[e] = h_; pbl[e] = l_;
            }
            *reinterpret_cast<ushort4v*>(&Ah[row][c4]) = pah;
            *reinterpret_cast<ushort4v*>(&Al[row][c4]) = pal;
            *reinterpret_cast<ushort4v*>(&Bh[row][c4]) = pbh;
            *reinterpret_cast<ushort4v*>(&Bl[row][c4]) = pbl;
        }
        __syncthreads();

        short8 ah[4], al[4], bh[4], bl[4];
#pragma unroll
        for (int mi = 0; mi < 4; mi++) {
            ah[mi] = *reinterpret_cast<const short8*>(&Ah[wm * 64 + mi * 16 + ar][kb]);
            al[mi] = *reinterpret_cast<const short8*>(&Al[wm * 64 + mi * 16 + ar][kb]);
        }
#pragma unroll
        for (int ni = 0; ni < 4; ni++) {
            bh[ni] = *reinterpret_cast<const short8*>(&Bh[wn * 64 + ni * 16 + ar][kb]);
            bl[ni] = *reinterpret_cast<const short8*>(&Bl[wn * 64 + ni * 16 + ar][kb]);
        }
#pragma unroll
        for (int mi = 0; mi < 4; mi++)
#pragma unroll
            for (int ni = 0; ni < 4; ni++) {
                acc[mi][ni] = __builtin_amdgcn_mfma_f32_16x16x32_bf16(ah[mi], bh[ni], acc[mi][ni], 0, 0, 0);
                acc[mi][ni] = __builtin_amdgcn_mfma_f32_16x16x32_bf16(al[mi], bh[ni], acc[mi][ni], 0, 0, 0);
                acc[mi][ni] = __builtin_amdgcn_mfma_f32_16x16x32_bf16(ah[mi], bl[ni], acc[mi][ni], 0, 0, 0);
            }
        __syncthreads();
    }

    // epilogue: D row = (lane>>4)*4 + r, col = lane&15
    const int r0 = (lane >> 4) * 4;
    const int cl = lane & 15;
#pragma unroll
    for (int mi = 0; mi < 4; mi++) {
#pragma unroll
        for (int ni = 0; ni < 4; ni++) {
            int col = n0 + wn * 64 + ni * 16 + cl;
            float bias = bih[col];
            size_t base = (size_t)(m0 + wm * 64 + mi * 16 + r0) * D_SZ + col;
#pragma unroll
            for (int r = 0; r < 4; r++)
                xp[base + (size_t)r * D_SZ] = acc[mi][ni][r] + bias;
        }
    }
}

// ---------------------------------------------------------------------------
// Kernel C: persistent recurrence, split-precision.
// 256 wgs = 8 batch groups (8 rows padded to 16) x 32 col groups (32 cols).
// Each wave holds its 16-col W_hh slice as hi+lo bf16 in registers (256 VGPR).
// h exchanged fp32 through hbuf; split to hi/lo LDS planes on staging.
// 3 independent 32-MFMA chains: Hh*Wh + Hl*Wh + Hh*Wl.
// ---------------------------------------------------------------------------
#define GC 32
#define MR 8
#define NC 32
#define HSTR (D_SZ + 8)   // 1032 bf16: breaks power-of-2 bank stride

__global__ __launch_bounds__(128, 1) void rnn_kernel(
    const float* __restrict__ xp, const float* __restrict__ Whh,
    const float* __restrict__ bhh, float* __restrict__ out,
    float* hbuf, int* cnt)
{
    __shared__ unsigned short Hh[16][HSTR];
    __shared__ unsigned short Hl[16][HSTR];

    const int wg = blockIdx.x;
    const int b  = wg & 7;      // batch group -> same-XCD heuristic
    const int c  = wg >> 3;     // col group
    const int tid  = threadIdx.x;
    const int lane = tid & 63, wave = tid >> 6;

    const int cl   = lane & 15;
    const int hi4  = lane >> 4;             // 0..3
    const int kb   = hi4 << 3;              // k-chunk base within 32
    const int colg = c * NC + wave * 16 + cl;
    const float bias = bhh[colg];
    const int rloc = hi4 * 4;
    const bool active = (hi4 < 2);          // D rows 0..7 are real

    // W_hh slice into registers (hi+lo): lane needs W_hh[colg][kk*32+kb+0..7]
    short8 wh[32], wl[32];
    {
        const float* wrow = Whh + (size_t)colg * D_SZ;
#pragma unroll
        for (int kk = 0; kk < 32; kk++) {
            f32x4 v0 = *reinterpret_cast<const f32x4*>(wrow + kk * 32 + kb);
            f32x4 v1 = *reinterpret_cast<const f32x4*>(wrow + kk * 32 + kb + 4);
            short8 sh, sl;
#pragma unroll
            for (int e = 0; e < 4; e++) {
                unsigned short h_, l_;
                split2p(v0[e], &h_, &l_); sh[e] = (short)h_; sl[e] = (short)l_;
                split2p(v1[e], &h_, &l_); sh[4 + e] = (short)h_; sl[4 + e] = (short)l_;
            }
            wh[kk] = sh; wl[kk] = sl;
        }
    }
    // zero both planes (h_0 = 0; rows 8..15 stay zero = M padding)
    for (int i = tid; i < 16 * HSTR; i += 128) {
        (&Hh[0][0])[i] = 0;
        (&Hl[0][0])[i] = 0;
    }
    __syncthreads();

    for (int t = 0; t < T_LEN; t++) {
        if (t > 0) {
            if (tid == 0) {
                const int target = GC * t;
                while (__hip_atomic_load(cnt + b, __ATOMIC_RELAXED, __HIP_MEMORY_SCOPE_AGENT) < target)
                    __builtin_amdgcn_s_sleep(1);
            }
            __syncthreads();
            __threadfence();   // acquire
            const float* hsrc = hbuf + ((size_t)(t & 1) * B_SZ + b * MR) * D_SZ;
#pragma unroll
            for (int i = 0; i < 16; i++) {
                int idx4 = tid + i * 128;           // 0..2047 f32x4 chunks
                int row  = idx4 >> 8;               // 256 chunks per row
                int c4   = (idx4 & 255) << 2;
                f32x4 v = *reinterpret_cast<const f32x4*>(hsrc + (size_t)row * D_SZ + c4);
                ushort4v vh, vl;
#pragma unroll
                for (int e = 0; e < 4; e++) {
                    unsigned short h_, l_;
                    split2p(v[e], &h_, &l_);
                    vh[e] = h_; vl[e] = l_;
                }
                *reinterpret_cast<ushort4v*>(&Hh[row][c4]) = vh;
                *reinterpret_cast<ushort4v*>(&Hl[row][c4]) = vl;
            }
            __syncthreads();
        }

        // S[0:16][16 cols] = H @ Wslice^T, 3 independent chains
        f32x4 a0 = (f32x4)0.0f, a1 = (f32x4)0.0f, a2 = (f32x4)0.0f;
#pragma unroll
        for (int kk = 0; kk < 32; kk++) {
            short8 ah  = *reinterpret_cast<const short8*>(&Hh[cl][kk * 32 + kb]);
            short8 alo = *reinterpret_cast<const short8*>(&Hl[cl][kk * 32 + kb]);
            a0 = __builtin_amdgcn_mfma_f32_16x16x32_bf16(ah,  wh[kk], a0, 0, 0, 0);
            a1 = __builtin_amdgcn_mfma_f32_16x16x32_bf16(alo, wh[kk], a1, 0, 0, 0);
            a2 = __builtin_amdgcn_mfma_f32_16x16x32_bf16(ah,  wl[kk], a2, 0, 0, 0);
        }

        if (active) {
            const float* xpt = xp + ((size_t)t * B_SZ + b * MR) * D_SZ;
            float* hdst = hbuf + ((size_t)((t + 1) & 1) * B_SZ + b * MR) * D_SZ;
            float* outt = out + ((size_t)t * B_SZ + b * MR) * D_SZ;
#pragma unroll
            for (int r = 0; r < 4; r++) {
                int row = rloc + r;   // 0..7
                float pre = (a0[r] + a1[r] + a2[r]) + xpt[(size_t)row * D_SZ + colg] + bias;
                float h = tanhf(pre);
                outt[(size_t)row * D_SZ + colg] = h;
                hdst[(size_t)row * D_SZ + colg] = h;
                if (t == T_LEN - 1)
                    out[(size_t)T_LEN * B_SZ * D_SZ + (size_t)(b * MR + row) * D_SZ + colg] = h;
            }
        }
        __threadfence();    // release: flush h stores
        __syncthreads();
        if (tid == 0)
            __hip_atomic_fetch_add(cnt + b, 1, __ATOMIC_RELEASE, __HIP_MEMORY_SCOPE_AGENT);
    }
}

// ---------------------------------------------------------------------------
extern "C" void kernel_launch(void* const* d_in, const int* in_sizes, int n_in,
                              void* d_out, int out_size, void* d_ws, size_t ws_size,
                              hipStream_t stream)
{
    const float* x   = (const float*)d_in[0];
    const float* Wih = (const float*)d_in[1];
    const float* Whh = (const float*)d_in[2];
    const float* bih = (const float*)d_in[3];
    const float* bhh = (const float*)d_in[4];
    float* out = (float*)d_out;

    char* ws = (char*)d_ws;
    float* xp   = (float*)ws;                               // 512*64*1024*4 = 134217728 B
    float* hbuf = (float*)(ws + 134217728);                 // 2*64*1024*4   = 524288 B
    int*   cnt  = (int*)(ws + 134217728 + 524288);          // 8 ints

    init_kernel<<<dim3(1), dim3(64), 0, stream>>>(cnt);
    xproj_kernel<<<dim3(2048), dim3(256), 0, stream>>>(x, Wih, bih, xp);
    rnn_kernel<<<dim3(256), dim3(128), 0, stream>>>(xp, Whh, bhh, out, hbuf, cnt);
}

// Round 5
// 7820.714 us; speedup vs baseline: 2.1341x; 2.1341x over previous
//
#include <hip/hip_runtime.h>
#include <hip/hip_bf16.h>

#define T_LEN 512
#define B_SZ  64
#define D_SZ  1024

typedef __attribute__((ext_vector_type(8))) short  short8;   // 8 bf16
typedef __attribute__((ext_vector_type(4))) float  f32x4;
typedef __attribute__((ext_vector_type(4))) unsigned short ushort4v;

__device__ __forceinline__ float bf2f(unsigned short u) {
    unsigned int x = ((unsigned int)u) << 16;
    return __uint_as_float(x);
}
__device__ __forceinline__ unsigned short f2bf(float f) {
    unsigned int x = __float_as_uint(f);
    unsigned int r = x + 0x7FFFu + ((x >> 16) & 1u);   // round-to-nearest-even
    return (unsigned short)(r >> 16);
}
// split via local temps (vector elements can't bind to references)
__device__ __forceinline__ void split2p(float f, unsigned short* hi, unsigned short* lo) {
    unsigned short h = f2bf(f);
    *hi = h;
    *lo = f2bf(f - bf2f(h));
}

// ---------------------------------------------------------------------------
// init: zero the per-batch-group counters (re-zeroed every launch so graph
// replays are deterministic)
// ---------------------------------------------------------------------------
__global__ void init_kernel(int* cnt) {
    if (threadIdx.x < 8) cnt[threadIdx.x] = 0;
}

// ---------------------------------------------------------------------------
// Kernel B: xproj[t,b,:] = x[t,b,:] @ W_ih^T + b_ih   (fp32 out)
// Split-precision: A,B -> (hi,lo) bf16; acc += Ah*Bh + Al*Bh + Ah*Bl.
// M = T*B = 32768, N = D = 1024, K = D = 1024; 128x128 tile, BK=32, 4 waves.
// ---------------------------------------------------------------------------
#define BM 128
#define BN 128
#define BK 32
#define ASTR (BK + 8)   // 40 bf16 rows -> 80 B stride, spreads banks

__global__ __launch_bounds__(256) void xproj_kernel(
    const float* __restrict__ x, const float* __restrict__ Wih,
    const float* __restrict__ bih, float* __restrict__ xp)
{
    __shared__ unsigned short Ah[BM][ASTR];
    __shared__ unsigned short Al[BM][ASTR];
    __shared__ unsigned short Bh[BN][ASTR];
    __shared__ unsigned short Bl[BN][ASTR];

    const int nblk = D_SZ / BN;                 // 8
    const int bm = blockIdx.x / nblk;
    const int bn = blockIdx.x % nblk;
    const int m0 = bm * BM, n0 = bn * BN;
    const int tid  = threadIdx.x;
    const int lane = tid & 63, wave = tid >> 6;
    const int wm = wave >> 1, wn = wave & 1;

    f32x4 acc[4][4];
#pragma unroll
    for (int i = 0; i < 4; i++)
#pragma unroll
        for (int j = 0; j < 4; j++) acc[i][j] = (f32x4)0.0f;

    const int ar = lane & 15;
    const int kb = (lane >> 4) << 3;            // 0,8,16,24

    for (int k0 = 0; k0 < D_SZ; k0 += BK) {
#pragma unroll
        for (int i = 0; i < 4; i++) {
            int f4  = tid + i * 256;            // 0..1023
            int row = f4 >> 3;
            int c4  = (f4 & 7) << 2;
            f32x4 va = *reinterpret_cast<const f32x4*>(x   + (size_t)(m0 + row) * D_SZ + k0 + c4);
            f32x4 vb = *reinterpret_cast<const f32x4*>(Wih + (size_t)(n0 + row) * D_SZ + k0 + c4);
            ushort4v pah, pal, pbh, pbl;
#pragma unroll
            for (int e = 0; e < 4; e++) {
                unsigned short h_, l_;
                split2p(va[e], &h_, &l_); pah[e] = h_; pal[e] = l_;
                split2p(vb[e], &h_, &l_); pbh[e] = h_; pbl[e] = l_;
            }
            *reinterpret_cast<ushort4v*>(&Ah[row][c4]) = pah;
            *reinterpret_cast<ushort4v*>(&Al[row][c4]) = pal;
            *reinterpret_cast<ushort4v*>(&Bh[row][c4]) = pbh;
            *reinterpret_cast<ushort4v*>(&Bl[row][c4]) = pbl;
        }
        __syncthreads();

        short8 ah[4], al[4], bh[4], bl[4];
#pragma unroll
        for (int mi = 0; mi < 4; mi++) {
            ah[mi] = *reinterpret_cast<const short8*>(&Ah[wm * 64 + mi * 16 + ar][kb]);
            al[mi] = *reinterpret_cast<const short8*>(&Al[wm * 64 + mi * 16 + ar][kb]);
        }
#pragma unroll
        for (int ni = 0; ni < 4; ni++) {
            bh[ni] = *reinterpret_cast<const short8*>(&Bh[wn * 64 + ni * 16 + ar][kb]);
            bl[ni] = *reinterpret_cast<const short8*>(&Bl[wn * 64 + ni * 16 + ar][kb]);
        }
#pragma unroll
        for (int mi = 0; mi < 4; mi++)
#pragma unroll
            for (int ni = 0; ni < 4; ni++) {
                acc[mi][ni] = __builtin_amdgcn_mfma_f32_16x16x32_bf16(ah[mi], bh[ni], acc[mi][ni], 0, 0, 0);
                acc[mi][ni] = __builtin_amdgcn_mfma_f32_16x16x32_bf16(al[mi], bh[ni], acc[mi][ni], 0, 0, 0);
                acc[mi][ni] = __builtin_amdgcn_mfma_f32_16x16x32_bf16(ah[mi], bl[ni], acc[mi][ni], 0, 0, 0);
            }
        __syncthreads();
    }

    // epilogue: D row = (lane>>4)*4 + r, col = lane&15
    const int r0 = (lane >> 4) * 4;
    const int cl = lane & 15;
#pragma unroll
    for (int mi = 0; mi < 4; mi++) {
#pragma unroll
        for (int ni = 0; ni < 4; ni++) {
            int col = n0 + wn * 64 + ni * 16 + cl;
            float bias = bih[col];
            size_t base = (size_t)(m0 + wm * 64 + mi * 16 + r0) * D_SZ + col;
#pragma unroll
            for (int r = 0; r < 4; r++)
                xp[base + (size_t)r * D_SZ] = acc[mi][ni][r] + bias;
        }
    }
}

// ---------------------------------------------------------------------------
// Kernel C: persistent recurrence, split-precision.
// 256 wgs = 8 batch groups (8 rows padded to 16) x 32 col groups (32 cols).
// Each wave holds its 16-col W_hh slice as hi+lo bf16 in registers (256 VGPR).
// h exchanged through hbuf via RELAXED AGENT-scope atomics (sc1: bypass the
// non-coherent per-XCD L2 to the coherence point). NO __threadfence anywhere:
// agent fences lower to full L2 writeback/invalidate on gfx950 (the R3
// 28us/step pathology). Ordering = vmcnt(0)+barrier before the counter add.
// Spin is BOUNDED so a protocol bug shows as absmax failure, not a GPU hang.
// ---------------------------------------------------------------------------
#define GC 32
#define MR 8
#define NC 32
#define HSTR (D_SZ + 8)   // 1032 bf16: breaks power-of-2 bank stride

__global__ __launch_bounds__(128, 1) void rnn_kernel(
    const float* __restrict__ xp, const float* __restrict__ Whh,
    const float* __restrict__ bhh, float* __restrict__ out,
    float* hbuf, int* cnt)
{
    __shared__ unsigned short Hh[16][HSTR];
    __shared__ unsigned short Hl[16][HSTR];

    const int wg = blockIdx.x;
    const int b  = wg & 7;      // batch group -> same-XCD heuristic
    const int c  = wg >> 3;     // col group
    const int tid  = threadIdx.x;
    const int lane = tid & 63, wave = tid >> 6;

    const int cl   = lane & 15;
    const int hi4  = lane >> 4;             // 0..3
    const int kb   = hi4 << 3;              // k-chunk base within 32
    const int colg = c * NC + wave * 16 + cl;
    const float bias = bhh[colg];
    const int rloc = hi4 * 4;
    const bool active = (hi4 < 2);          // D rows 0..7 are real

    // W_hh slice into registers (hi+lo): lane needs W_hh[colg][kk*32+kb+0..7]
    short8 wh[32], wl[32];
    {
        const float* wrow = Whh + (size_t)colg * D_SZ;
#pragma unroll
        for (int kk = 0; kk < 32; kk++) {
            f32x4 v0 = *reinterpret_cast<const f32x4*>(wrow + kk * 32 + kb);
            f32x4 v1 = *reinterpret_cast<const f32x4*>(wrow + kk * 32 + kb + 4);
            short8 sh, sl;
#pragma unroll
            for (int e = 0; e < 4; e++) {
                unsigned short h_, l_;
                split2p(v0[e], &h_, &l_); sh[e] = (short)h_; sl[e] = (short)l_;
                split2p(v1[e], &h_, &l_); sh[4 + e] = (short)h_; sl[4 + e] = (short)l_;
            }
            wh[kk] = sh; wl[kk] = sl;
        }
    }
    // zero both planes (h_0 = 0; rows 8..15 stay zero = M padding)
    for (int i = tid; i < 16 * HSTR; i += 128) {
        (&Hh[0][0])[i] = 0;
        (&Hl[0][0])[i] = 0;
    }
    __syncthreads();

    for (int t = 0; t < T_LEN; t++) {
        if (t > 0) {
            if (tid == 0) {
                const int target = GC * t;
                // bounded spin: ~4e8 iters ~= seconds; a protocol bug then
                // produces wrong data (absmax fail) instead of a hard hang.
                for (long it = 0; it < 400000000L; ++it) {
                    if (__hip_atomic_load(cnt + b, __ATOMIC_RELAXED, __HIP_MEMORY_SCOPE_AGENT) >= target)
                        break;
                    __builtin_amdgcn_s_sleep(1);
                }
            }
            __syncthreads();
            // stage h: 8 rows x 1024 f32 = 4096 ull chunks, 32 per thread,
            // loaded as relaxed agent atomics (coherent, no cache flush)
            const unsigned long long* hsrc8 = reinterpret_cast<const unsigned long long*>(
                hbuf + ((size_t)(t & 1) * B_SZ + b * MR) * D_SZ);
#pragma unroll
            for (int i = 0; i < 32; i++) {
                int j   = tid + i * 128;        // 0..4095
                int row = j >> 9;               // 512 ull per row
                int c2  = (j & 511) << 1;
                unsigned long long v8 = __hip_atomic_load(hsrc8 + j, __ATOMIC_RELAXED, __HIP_MEMORY_SCOPE_AGENT);
                float f0 = __uint_as_float((unsigned int)(v8 & 0xFFFFFFFFull));
                float f1 = __uint_as_float((unsigned int)(v8 >> 32));
                unsigned short h0, l0, h1, l1;
                split2p(f0, &h0, &l0);
                split2p(f1, &h1, &l1);
                *reinterpret_cast<unsigned int*>(&Hh[row][c2]) = (unsigned int)h0 | ((unsigned int)h1 << 16);
                *reinterpret_cast<unsigned int*>(&Hl[row][c2]) = (unsigned int)l0 | ((unsigned int)l1 << 16);
            }
            __syncthreads();
        }

        // S[0:16][16 cols] = H @ Wslice^T, 3 independent chains
        f32x4 a0 = (f32x4)0.0f, a1 = (f32x4)0.0f, a2 = (f32x4)0.0f;
#pragma unroll
        for (int kk = 0; kk < 32; kk++) {
            short8 ah  = *reinterpret_cast<const short8*>(&Hh[cl][kk * 32 + kb]);
            short8 alo = *reinterpret_cast<const short8*>(&Hl[cl][kk * 32 + kb]);
            a0 = __builtin_amdgcn_mfma_f32_16x16x32_bf16(ah,  wh[kk], a0, 0, 0, 0);
            a1 = __builtin_amdgcn_mfma_f32_16x16x32_bf16(alo, wh[kk], a1, 0, 0, 0);
            a2 = __builtin_amdgcn_mfma_f32_16x16x32_bf16(ah,  wl[kk], a2, 0, 0, 0);
        }

        if (active) {
            const float* xpt = xp + ((size_t)t * B_SZ + b * MR) * D_SZ;
            float* hdst = hbuf + ((size_t)((t + 1) & 1) * B_SZ + b * MR) * D_SZ;
            float* outt = out + ((size_t)t * B_SZ + b * MR) * D_SZ;
#pragma unroll
            for (int r = 0; r < 4; r++) {
                int row = rloc + r;   // 0..7
                float pre = (a0[r] + a1[r] + a2[r]) + xpt[(size_t)row * D_SZ + colg] + bias;
                float h = tanhf(pre);
                outt[(size_t)row * D_SZ + colg] = h;
                __hip_atomic_store(&hdst[(size_t)row * D_SZ + colg], h,
                                   __ATOMIC_RELAXED, __HIP_MEMORY_SCOPE_AGENT);
                if (t == T_LEN - 1)
                    out[(size_t)T_LEN * B_SZ * D_SZ + (size_t)(b * MR + row) * D_SZ + colg] = h;
            }
        }
        // drain the sc1 h-stores to the coherence point, then publish.
        asm volatile("s_waitcnt vmcnt(0)" ::: "memory");
        __syncthreads();
        if (tid == 0)
            __hip_atomic_fetch_add(cnt + b, 1, __ATOMIC_RELAXED, __HIP_MEMORY_SCOPE_AGENT);
    }
}

// ---------------------------------------------------------------------------
extern "C" void kernel_launch(void* const* d_in, const int* in_sizes, int n_in,
                              void* d_out, int out_size, void* d_ws, size_t ws_size,
                              hipStream_t stream)
{
    const float* x   = (const float*)d_in[0];
    const float* Wih = (const float*)d_in[1];
    const float* Whh = (const float*)d_in[2];
    const float* bih = (const float*)d_in[3];
    const float* bhh = (const float*)d_in[4];
    float* out = (float*)d_out;

    char* ws = (char*)d_ws;
    float* xp   = (float*)ws;                               // 512*64*1024*4 = 134217728 B
    float* hbuf = (float*)(ws + 134217728);                 // 2*64*1024*4   = 524288 B
    int*   cnt  = (int*)(ws + 134217728 + 524288);          // 8 ints

    init_kernel<<<dim3(1), dim3(64), 0, stream>>>(cnt);
    xproj_kernel<<<dim3(2048), dim3(256), 0, stream>>>(x, Wih, bih, xp);
    rnn_kernel<<<dim3(256), dim3(128), 0, stream>>>(xp, Whh, bhh, out, hbuf, cnt);
}

// Round 6
// 6728.339 us; speedup vs baseline: 2.4806x; 1.1624x over previous
//
#include <hip/hip_runtime.h>
#include <hip/hip_bf16.h>

#define T_LEN 512
#define B_SZ  64
#define D_SZ  1024

typedef __attribute__((ext_vector_type(8))) short  short8;   // 8 bf16
typedef __attribute__((ext_vector_type(4))) float  f32x4;
typedef __attribute__((ext_vector_type(4))) unsigned short ushort4v;

__device__ __forceinline__ float bf2f(unsigned short u) {
    unsigned int x = ((unsigned int)u) << 16;
    return __uint_as_float(x);
}
__device__ __forceinline__ unsigned short f2bf(float f) {
    unsigned int x = __float_as_uint(f);
    unsigned int r = x + 0x7FFFu + ((x >> 16) & 1u);   // round-to-nearest-even
    return (unsigned short)(r >> 16);
}
// split via local temps (vector elements can't bind to references)
__device__ __forceinline__ void split2p(float f, unsigned short* hi, unsigned short* lo) {
    unsigned short h = f2bf(f);
    *hi = h;
    *lo = f2bf(f - bf2f(h));
}

// ---------------------------------------------------------------------------
// Sync layout: 8 teams x 64 ints (256 B) -> each team's 32 producer slots
// live in their own cacheline; no cross-team line sharing, no RMWs ever.
// ---------------------------------------------------------------------------
#define CNT_STRIDE 64

__global__ void init_kernel(int* slot) {
    int i = threadIdx.x;
    if (i < 8 * CNT_STRIDE) slot[i] = 0;
}

// ---------------------------------------------------------------------------
// Kernel B: xproj[t,b,:] = x[t,b,:] @ W_ih^T + b_ih   (fp32 out)
// Split-precision: A,B -> (hi,lo) bf16; acc += Ah*Bh + Al*Bh + Ah*Bl.
// M = T*B = 32768, N = D = 1024, K = D = 1024; 128x128 tile, BK=32, 4 waves.
// ---------------------------------------------------------------------------
#define BM 128
#define BN 128
#define BK 32
#define ASTR (BK + 8)   // 40 bf16 rows -> 80 B stride, spreads banks

__global__ __launch_bounds__(256) void xproj_kernel(
    const float* __restrict__ x, const float* __restrict__ Wih,
    const float* __restrict__ bih, float* __restrict__ xp)
{
    __shared__ unsigned short Ah[BM][ASTR];
    __shared__ unsigned short Al[BM][ASTR];
    __shared__ unsigned short Bh[BN][ASTR];
    __shared__ unsigned short Bl[BN][ASTR];

    const int nblk = D_SZ / BN;                 // 8
    const int bm = blockIdx.x / nblk;
    const int bn = blockIdx.x % nblk;
    const int m0 = bm * BM, n0 = bn * BN;
    const int tid  = threadIdx.x;
    const int lane = tid & 63, wave = tid >> 6;
    const int wm = wave >> 1, wn = wave & 1;

    f32x4 acc[4][4];
#pragma unroll
    for (int i = 0; i < 4; i++)
#pragma unroll
        for (int j = 0; j < 4; j++) acc[i][j] = (f32x4)0.0f;

    const int ar = lane & 15;
    const int kb = (lane >> 4) << 3;            // 0,8,16,24

    for (int k0 = 0; k0 < D_SZ; k0 += BK) {
#pragma unroll
        for (int i = 0; i < 4; i++) {
            int f4  = tid + i * 256;            // 0..1023
            int row = f4 >> 3;
            int c4  = (f4 & 7) << 2;
            f32x4 va = *reinterpret_cast<const f32x4*>(x   + (size_t)(m0 + row) * D_SZ + k0 + c4);
            f32x4 vb = *reinterpret_cast<const f32x4*>(Wih + (size_t)(n0 + row) * D_SZ + k0 + c4);
            ushort4v pah, pal, pbh, pbl;
#pragma unroll
            for (int e = 0; e < 4; e++) {
                unsigned short h_, l_;
                split2p(va[e], &h_, &l_); pah[e] = h_; pal[e] = l_;
                split2p(vb[e], &h_, &l_); pbh[e] = h_; pbl[e] = l_;
            }
            *reinterpret_cast<ushort4v*>(&Ah[row][c4]) = pah;
            *reinterpret_cast<ushort4v*>(&Al[row][c4]) = pal;
            *reinterpret_cast<ushort4v*>(&Bh[row][c4]) = pbh;
            *reinterpret_cast<ushort4v*>(&Bl[row][c4]) = pbl;
        }
        __syncthreads();

        short8 ah[4], al[4], bh[4], bl[4];
#pragma unroll
        for (int mi = 0; mi < 4; mi++) {
            ah[mi] = *reinterpret_cast<const short8*>(&Ah[wm * 64 + mi * 16 + ar][kb]);
            al[mi] = *reinterpret_cast<const short8*>(&Al[wm * 64 + mi * 16 + ar][kb]);
        }
#pragma unroll
        for (int ni = 0; ni < 4; ni++) {
            bh[ni] = *reinterpret_cast<const short8*>(&Bh[wn * 64 + ni * 16 + ar][kb]);
            bl[ni] = *reinterpret_cast<const short8*>(&Bl[wn * 64 + ni * 16 + ar][kb]);
        }
#pragma unroll
        for (int mi = 0; mi < 4; mi++)
#pragma unroll
            for (int ni = 0; ni < 4; ni++) {
                acc[mi][ni] = __builtin_amdgcn_mfma_f32_16x16x32_bf16(ah[mi], bh[ni], acc[mi][ni], 0, 0, 0);
                acc[mi][ni] = __builtin_amdgcn_mfma_f32_16x16x32_bf16(al[mi], bh[ni], acc[mi][ni], 0, 0, 0);
                acc[mi][ni] = __builtin_amdgcn_mfma_f32_16x16x32_bf16(ah[mi], bl[ni], acc[mi][ni], 0, 0, 0);
            }
        __syncthreads();
    }

    // epilogue: D row = (lane>>4)*4 + r, col = lane&15
    const int r0 = (lane >> 4) * 4;
    const int cl = lane & 15;
#pragma unroll
    for (int mi = 0; mi < 4; mi++) {
#pragma unroll
        for (int ni = 0; ni < 4; ni++) {
            int col = n0 + wn * 64 + ni * 16 + cl;
            float bias = bih[col];
            size_t base = (size_t)(m0 + wm * 64 + mi * 16 + r0) * D_SZ + col;
#pragma unroll
            for (int r = 0; r < 4; r++)
                xp[base + (size_t)r * D_SZ] = acc[mi][ni][r] + bias;
        }
    }
}

// ---------------------------------------------------------------------------
// Kernel C: persistent recurrence, split-precision.
// 256 wgs = 8 teams (8 batch rows, padded to 16) x 32 col groups (32 cols).
// Publish protocol (no RMW, no shared lines): producer wg (b,c) stores step
// number to slot[b*64+c] (own team line); consumers poll their team line with
// ONE coalesced 128B load + ballot. h exchanged via relaxed sc1 atomics.
// xp tile for step t prefetched before the wait (hides HBM latency).
// ---------------------------------------------------------------------------
#define MR 8
#define NC 32
#define HSTR (D_SZ + 8)   // 1032 bf16: breaks power-of-2 bank stride

__global__ __launch_bounds__(128, 1) void rnn_kernel(
    const float* __restrict__ xp, const float* __restrict__ Whh,
    const float* __restrict__ bhh, float* __restrict__ out,
    float* hbuf, int* slot)
{
    __shared__ unsigned short Hh[16][HSTR];
    __shared__ unsigned short Hl[16][HSTR];

    const int wg = blockIdx.x;
    const int b  = wg & 7;      // team (batch group) -> same-XCD heuristic
    const int c  = wg >> 3;     // col group
    const int tid  = threadIdx.x;
    const int lane = tid & 63, wave = tid >> 6;

    const int cl   = lane & 15;
    const int hi4  = lane >> 4;             // 0..3
    const int kb   = hi4 << 3;              // k-chunk base within 32
    const int colg = c * NC + wave * 16 + cl;
    const float bias = bhh[colg];
    const int rloc = hi4 * 4;
    const bool active = (hi4 < 2);          // D rows 0..7 are real

    int* tslot = slot + b * CNT_STRIDE;     // this team's 32 publish slots

    // W_hh slice into registers (hi+lo): lane needs W_hh[colg][kk*32+kb+0..7]
    short8 wh[32], wl[32];
    {
        const float* wrow = Whh + (size_t)colg * D_SZ;
#pragma unroll
        for (int kk = 0; kk < 32; kk++) {
            f32x4 v0 = *reinterpret_cast<const f32x4*>(wrow + kk * 32 + kb);
            f32x4 v1 = *reinterpret_cast<const f32x4*>(wrow + kk * 32 + kb + 4);
            short8 sh, sl;
#pragma unroll
            for (int e = 0; e < 4; e++) {
                unsigned short h_, l_;
                split2p(v0[e], &h_, &l_); sh[e] = (short)h_; sl[e] = (short)l_;
                split2p(v1[e], &h_, &l_); sh[4 + e] = (short)h_; sl[4 + e] = (short)l_;
            }
            wh[kk] = sh; wl[kk] = sl;
        }
    }
    // zero both planes (h_0 = 0; rows 8..15 stay zero = M padding)
    for (int i = tid; i < 16 * HSTR; i += 128) {
        (&Hh[0][0])[i] = 0;
        (&Hl[0][0])[i] = 0;
    }
    __syncthreads();

    for (int t = 0; t < T_LEN; t++) {
        // ---- prefetch this step's xp values (independent of h) ----
        float xv[4];
        const float* xpt = xp + ((size_t)t * B_SZ + b * MR) * D_SZ;
        if (active) {
#pragma unroll
            for (int r = 0; r < 4; r++)
                xv[r] = xpt[(size_t)(rloc + r) * D_SZ + colg];
        }

        if (t > 0) {
            // wave 0 polls the team line: one coalesced 128B load + ballot
            if (wave == 0) {
                for (long it = 0; it < 200000000L; ++it) {
                    int v = __hip_atomic_load(tslot + (lane & 31), __ATOMIC_RELAXED, __HIP_MEMORY_SCOPE_AGENT);
                    if (__all(v >= t)) break;
                    __builtin_amdgcn_s_sleep(1);
                }
            }
            __syncthreads();
            // stage h: 8 rows x 1024 f32 = 4096 ull chunks, 32 per thread,
            // loaded as relaxed agent atomics (coherent, no cache flush)
            const unsigned long long* hsrc8 = reinterpret_cast<const unsigned long long*>(
                hbuf + ((size_t)(t & 1) * B_SZ + b * MR) * D_SZ);
#pragma unroll
            for (int i = 0; i < 32; i++) {
                int j   = tid + i * 128;        // 0..4095
                int row = j >> 9;               // 512 ull per row
                int c2  = (j & 511) << 1;
                unsigned long long v8 = __hip_atomic_load(hsrc8 + j, __ATOMIC_RELAXED, __HIP_MEMORY_SCOPE_AGENT);
                float f0 = __uint_as_float((unsigned int)(v8 & 0xFFFFFFFFull));
                float f1 = __uint_as_float((unsigned int)(v8 >> 32));
                unsigned short h0, l0, h1, l1;
                split2p(f0, &h0, &l0);
                split2p(f1, &h1, &l1);
                *reinterpret_cast<unsigned int*>(&Hh[row][c2]) = (unsigned int)h0 | ((unsigned int)h1 << 16);
                *reinterpret_cast<unsigned int*>(&Hl[row][c2]) = (unsigned int)l0 | ((unsigned int)l1 << 16);
            }
            __syncthreads();
        }

        // S[0:16][16 cols] = H @ Wslice^T, 3 independent chains
        f32x4 a0 = (f32x4)0.0f, a1 = (f32x4)0.0f, a2 = (f32x4)0.0f;
#pragma unroll
        for (int kk = 0; kk < 32; kk++) {
            short8 ah  = *reinterpret_cast<const short8*>(&Hh[cl][kk * 32 + kb]);
            short8 alo = *reinterpret_cast<const short8*>(&Hl[cl][kk * 32 + kb]);
            a0 = __builtin_amdgcn_mfma_f32_16x16x32_bf16(ah,  wh[kk], a0, 0, 0, 0);
            a1 = __builtin_amdgcn_mfma_f32_16x16x32_bf16(alo, wh[kk], a1, 0, 0, 0);
            a2 = __builtin_amdgcn_mfma_f32_16x16x32_bf16(ah,  wl[kk], a2, 0, 0, 0);
        }

        if (active) {
            float* hdst = hbuf + ((size_t)((t + 1) & 1) * B_SZ + b * MR) * D_SZ;
            float* outt = out + ((size_t)t * B_SZ + b * MR) * D_SZ;
#pragma unroll
            for (int r = 0; r < 4; r++) {
                int row = rloc + r;   // 0..7
                float pre = (a0[r] + a1[r] + a2[r]) + xv[r] + bias;
                float h = tanhf(pre);
                outt[(size_t)row * D_SZ + colg] = h;
                __hip_atomic_store(&hdst[(size_t)row * D_SZ + colg], h,
                                   __ATOMIC_RELAXED, __HIP_MEMORY_SCOPE_AGENT);
                if (t == T_LEN - 1)
                    out[(size_t)T_LEN * B_SZ * D_SZ + (size_t)(b * MR + row) * D_SZ + colg] = h;
            }
        }
        // drain the sc1 h-stores to the coherence point, then publish.
        asm volatile("s_waitcnt vmcnt(0)" ::: "memory");
        __syncthreads();
        if (tid == 0)
            __hip_atomic_store(tslot + c, t + 1, __ATOMIC_RELAXED, __HIP_MEMORY_SCOPE_AGENT);
    }
}

// ---------------------------------------------------------------------------
extern "C" void kernel_launch(void* const* d_in, const int* in_sizes, int n_in,
                              void* d_out, int out_size, void* d_ws, size_t ws_size,
                              hipStream_t stream)
{
    const float* x   = (const float*)d_in[0];
    const float* Wih = (const float*)d_in[1];
    const float* Whh = (const float*)d_in[2];
    const float* bih = (const float*)d_in[3];
    const float* bhh = (const float*)d_in[4];
    float* out = (float*)d_out;

    char* ws = (char*)d_ws;
    float* xp   = (float*)ws;                               // 512*64*1024*4 = 134217728 B
    float* hbuf = (float*)(ws + 134217728);                 // 2*64*1024*4   = 524288 B
    int*   slot = (int*)(ws + 134217728 + 524288);          // 8*64 ints = 2048 B

    init_kernel<<<dim3(1), dim3(512), 0, stream>>>(slot);
    xproj_kernel<<<dim3(2048), dim3(256), 0, stream>>>(x, Wih, bih, xp);
    rnn_kernel<<<dim3(256), dim3(128), 0, stream>>>(xp, Whh, bhh, out, hbuf, slot);
}

// Round 7
// 3330.260 us; speedup vs baseline: 5.0117x; 2.0204x over previous
//
#include <hip/hip_runtime.h>
#include <hip/hip_bf16.h>

#define T_LEN 512
#define B_SZ  64
#define D_SZ  1024

typedef __attribute__((ext_vector_type(8))) short  short8;   // 8 bf16
typedef __attribute__((ext_vector_type(4))) float  f32x4;
typedef __attribute__((ext_vector_type(4))) unsigned short ushort4v;

__device__ __forceinline__ float bf2f(unsigned short u) {
    unsigned int x = ((unsigned int)u) << 16;
    return __uint_as_float(x);
}
__device__ __forceinline__ unsigned short f2bf(float f) {
    unsigned int x = __float_as_uint(f);
    unsigned int r = x + 0x7FFFu + ((x >> 16) & 1u);   // round-to-nearest-even
    return (unsigned short)(r >> 16);
}
// split via local temps (vector elements can't bind to references)
__device__ __forceinline__ void split2p(float f, unsigned short* hi, unsigned short* lo) {
    unsigned short h = f2bf(f);
    *hi = h;
    *lo = f2bf(f - bf2f(h));
}

// ---------------------------------------------------------------------------
// Sync layout: 8 teams x 64 ints (256 B) -> each team's 32 producer slots
// live in their own cacheline; no cross-team line sharing, no RMWs ever.
// ---------------------------------------------------------------------------
#define CNT_STRIDE 64

__global__ void init_kernel(int* slot) {
    int i = threadIdx.x;
    if (i < 8 * CNT_STRIDE) slot[i] = 0;
}

// ---------------------------------------------------------------------------
// Kernel B: xproj[t,b,:] = x[t,b,:] @ W_ih^T + b_ih   (fp32 out)
// Split-precision: A,B -> (hi,lo) bf16; acc += Ah*Bh + Al*Bh + Ah*Bl.
// M = T*B = 32768, N = D = 1024, K = D = 1024; 128x128 tile, BK=32, 4 waves.
// ---------------------------------------------------------------------------
#define BM 128
#define BN 128
#define BK 32
#define ASTR (BK + 8)   // 40 bf16 rows -> 80 B stride, spreads banks

__global__ __launch_bounds__(256) void xproj_kernel(
    const float* __restrict__ x, const float* __restrict__ Wih,
    const float* __restrict__ bih, float* __restrict__ xp)
{
    __shared__ unsigned short Ah[BM][ASTR];
    __shared__ unsigned short Al[BM][ASTR];
    __shared__ unsigned short Bh[BN][ASTR];
    __shared__ unsigned short Bl[BN][ASTR];

    const int nblk = D_SZ / BN;                 // 8
    const int bm = blockIdx.x / nblk;
    const int bn = blockIdx.x % nblk;
    const int m0 = bm * BM, n0 = bn * BN;
    const int tid  = threadIdx.x;
    const int lane = tid & 63, wave = tid >> 6;
    const int wm = wave >> 1, wn = wave & 1;

    f32x4 acc[4][4];
#pragma unroll
    for (int i = 0; i < 4; i++)
#pragma unroll
        for (int j = 0; j < 4; j++) acc[i][j] = (f32x4)0.0f;

    const int ar = lane & 15;
    const int kb = (lane >> 4) << 3;            // 0,8,16,24

    for (int k0 = 0; k0 < D_SZ; k0 += BK) {
#pragma unroll
        for (int i = 0; i < 4; i++) {
            int f4  = tid + i * 256;            // 0..1023
            int row = f4 >> 3;
            int c4  = (f4 & 7) << 2;
            f32x4 va = *reinterpret_cast<const f32x4*>(x   + (size_t)(m0 + row) * D_SZ + k0 + c4);
            f32x4 vb = *reinterpret_cast<const f32x4*>(Wih + (size_t)(n0 + row) * D_SZ + k0 + c4);
            ushort4v pah, pal, pbh, pbl;
#pragma unroll
            for (int e = 0; e < 4; e++) {
                unsigned short h_, l_;
                split2p(va[e], &h_, &l_); pah[e] = h_; pal[e] = l_;
                split2p(vb[e], &h_, &l_); pbh[e] = h_; pbl[e] = l_;
            }
            *reinterpret_cast<ushort4v*>(&Ah[row][c4]) = pah;
            *reinterpret_cast<ushort4v*>(&Al[row][c4]) = pal;
            *reinterpret_cast<ushort4v*>(&Bh[row][c4]) = pbh;
            *reinterpret_cast<ushort4v*>(&Bl[row][c4]) = pbl;
        }
        __syncthreads();

        short8 ah[4], al[4], bh[4], bl[4];
#pragma unroll
        for (int mi = 0; mi < 4; mi++) {
            ah[mi] = *reinterpret_cast<const short8*>(&Ah[wm * 64 + mi * 16 + ar][kb]);
            al[mi] = *reinterpret_cast<const short8*>(&Al[wm * 64 + mi * 16 + ar][kb]);
        }
#pragma unroll
        for (int ni = 0; ni < 4; ni++) {
            bh[ni] = *reinterpret_cast<const short8*>(&Bh[wn * 64 + ni * 16 + ar][kb]);
            bl[ni] = *reinterpret_cast<const short8*>(&Bl[wn * 64 + ni * 16 + ar][kb]);
        }
#pragma unroll
        for (int mi = 0; mi < 4; mi++)
#pragma unroll
            for (int ni = 0; ni < 4; ni++) {
                acc[mi][ni] = __builtin_amdgcn_mfma_f32_16x16x32_bf16(ah[mi], bh[ni], acc[mi][ni], 0, 0, 0);
                acc[mi][ni] = __builtin_amdgcn_mfma_f32_16x16x32_bf16(al[mi], bh[ni], acc[mi][ni], 0, 0, 0);
                acc[mi][ni] = __builtin_amdgcn_mfma_f32_16x16x32_bf16(ah[mi], bl[ni], acc[mi][ni], 0, 0, 0);
            }
        __syncthreads();
    }

    // epilogue: D row = (lane>>4)*4 + r, col = lane&15
    const int r0 = (lane >> 4) * 4;
    const int cl = lane & 15;
#pragma unroll
    for (int mi = 0; mi < 4; mi++) {
#pragma unroll
        for (int ni = 0; ni < 4; ni++) {
            int col = n0 + wn * 64 + ni * 16 + cl;
            float bias = bih[col];
            size_t base = (size_t)(m0 + wm * 64 + mi * 16 + r0) * D_SZ + col;
#pragma unroll
            for (int r = 0; r < 4; r++)
                xp[base + (size_t)r * D_SZ] = acc[mi][ni][r] + bias;
        }
    }
}

// ---------------------------------------------------------------------------
// Kernel C: persistent recurrence, split-precision.
// 256 wgs = 8 teams (8 batch rows, padded to 16) x 32 col groups (32 cols).
// h exchanged as PACKED (hi|lo<<16) uint via relaxed sc1 atomics -- split
// computed once by the producer. Consumer stages with CHUNKED load-then-use
// (8 atomic loads batched -> pipelined, not 32 serialized round trips, which
// was R6's 11 us/step). Publish = slot-line store; poll = coalesced ballot.
// ---------------------------------------------------------------------------
#define MR 8
#define NC 32
#define HSTR (D_SZ + 8)   // 1032 bf16: breaks power-of-2 bank stride

__global__ __launch_bounds__(128, 1) void rnn_kernel(
    const float* __restrict__ xp, const float* __restrict__ Whh,
    const float* __restrict__ bhh, float* __restrict__ out,
    unsigned int* hbuf, int* slot)
{
    __shared__ unsigned short Hh[16][HSTR];
    __shared__ unsigned short Hl[16][HSTR];

    const int wg = blockIdx.x;
    const int b  = wg & 7;      // team (batch group) -> same-XCD heuristic
    const int c  = wg >> 3;     // col group
    const int tid  = threadIdx.x;
    const int lane = tid & 63, wave = tid >> 6;

    const int cl   = lane & 15;
    const int hi4  = lane >> 4;             // 0..3
    const int kb   = hi4 << 3;              // k-chunk base within 32
    const int colg = c * NC + wave * 16 + cl;
    const float bias = bhh[colg];
    const int rloc = hi4 * 4;
    const bool active = (hi4 < 2);          // D rows 0..7 are real

    int* tslot = slot + b * CNT_STRIDE;     // this team's 32 publish slots

    // W_hh slice into registers (hi+lo): lane needs W_hh[colg][kk*32+kb+0..7]
    short8 wh[32], wl[32];
    {
        const float* wrow = Whh + (size_t)colg * D_SZ;
#pragma unroll
        for (int kk = 0; kk < 32; kk++) {
            f32x4 v0 = *reinterpret_cast<const f32x4*>(wrow + kk * 32 + kb);
            f32x4 v1 = *reinterpret_cast<const f32x4*>(wrow + kk * 32 + kb + 4);
            short8 sh, sl;
#pragma unroll
            for (int e = 0; e < 4; e++) {
                unsigned short h_, l_;
                split2p(v0[e], &h_, &l_); sh[e] = (short)h_; sl[e] = (short)l_;
                split2p(v1[e], &h_, &l_); sh[4 + e] = (short)h_; sl[4 + e] = (short)l_;
            }
            wh[kk] = sh; wl[kk] = sl;
        }
    }
    // zero both planes (h_0 = 0; rows 8..15 stay zero = M padding)
    for (int i = tid; i < 16 * HSTR; i += 128) {
        (&Hh[0][0])[i] = 0;
        (&Hl[0][0])[i] = 0;
    }
    __syncthreads();

    for (int t = 0; t < T_LEN; t++) {
        // ---- prefetch this step's xp values (independent of h) ----
        float xv[4];
        const float* xpt = xp + ((size_t)t * B_SZ + b * MR) * D_SZ;
        if (active) {
#pragma unroll
            for (int r = 0; r < 4; r++)
                xv[r] = xpt[(size_t)(rloc + r) * D_SZ + colg];
        }

        if (t > 0) {
            // wave 0 polls the team line: one coalesced 128B load + ballot
            if (wave == 0) {
                for (long it = 0; it < 200000000L; ++it) {
                    int v = __hip_atomic_load(tslot + (lane & 31), __ATOMIC_RELAXED, __HIP_MEMORY_SCOPE_AGENT);
                    if (__all(v >= t)) break;
                    __builtin_amdgcn_s_sleep(1);
                }
            }
            __syncthreads();
            // stage h: 8 rows x 1024 packed uints = 4096 ull chunks, 32/thread,
            // in 4 chunks of 8: loads batched (pipeline) then unpacked (bit ops)
            const unsigned long long* hsrc8 = reinterpret_cast<const unsigned long long*>(
                hbuf + ((size_t)(t & 1) * B_SZ + b * MR) * D_SZ);
#pragma unroll
            for (int ch = 0; ch < 4; ch++) {
                unsigned long long vv[8];
#pragma unroll
                for (int i = 0; i < 8; i++)
                    vv[i] = __hip_atomic_load(hsrc8 + tid + (ch * 8 + i) * 128,
                                              __ATOMIC_RELAXED, __HIP_MEMORY_SCOPE_AGENT);
#pragma unroll
                for (int i = 0; i < 8; i++) {
                    int j   = tid + (ch * 8 + i) * 128;   // 0..4095
                    int row = j >> 9;                     // 512 ull per row
                    int c2  = (j & 511) << 1;
                    unsigned int p0 = (unsigned int)(vv[i] & 0xFFFFFFFFull);  // hi|lo<<16
                    unsigned int p1 = (unsigned int)(vv[i] >> 32);
                    *reinterpret_cast<unsigned int*>(&Hh[row][c2]) = (p0 & 0xFFFFu) | (p1 << 16);
                    *reinterpret_cast<unsigned int*>(&Hl[row][c2]) = (p0 >> 16) | (p1 & 0xFFFF0000u);
                }
            }
            __syncthreads();
        }

        // S[0:16][16 cols] = H @ Wslice^T, 3 independent chains
        f32x4 a0 = (f32x4)0.0f, a1 = (f32x4)0.0f, a2 = (f32x4)0.0f;
#pragma unroll
        for (int kk = 0; kk < 32; kk++) {
            short8 ah  = *reinterpret_cast<const short8*>(&Hh[cl][kk * 32 + kb]);
            short8 alo = *reinterpret_cast<const short8*>(&Hl[cl][kk * 32 + kb]);
            a0 = __builtin_amdgcn_mfma_f32_16x16x32_bf16(ah,  wh[kk], a0, 0, 0, 0);
            a1 = __builtin_amdgcn_mfma_f32_16x16x32_bf16(alo, wh[kk], a1, 0, 0, 0);
            a2 = __builtin_amdgcn_mfma_f32_16x16x32_bf16(ah,  wl[kk], a2, 0, 0, 0);
        }

        float hval[4];
        if (active) {
            unsigned int* hdst = hbuf + ((size_t)((t + 1) & 1) * B_SZ + b * MR) * D_SZ;
#pragma unroll
            for (int r = 0; r < 4; r++) {
                int row = rloc + r;   // 0..7
                float pre = (a0[r] + a1[r] + a2[r]) + xv[r] + bias;
                float h = tanhf(pre);
                hval[r] = h;
                unsigned short hh_, ll_;
                split2p(h, &hh_, &ll_);
                unsigned int packed = (unsigned int)hh_ | ((unsigned int)ll_ << 16);
                __hip_atomic_store(&hdst[(size_t)row * D_SZ + colg], packed,
                                   __ATOMIC_RELAXED, __HIP_MEMORY_SCOPE_AGENT);
            }
        }
        // drain the sc1 h-stores to the coherence point, then publish.
        asm volatile("s_waitcnt vmcnt(0)" ::: "memory");
        __syncthreads();
        if (tid == 0)
            __hip_atomic_store(tslot + c, t + 1, __ATOMIC_RELAXED, __HIP_MEMORY_SCOPE_AGENT);

        // out stores AFTER publish: off the inter-team critical path
        if (active) {
            float* outt = out + ((size_t)t * B_SZ + b * MR) * D_SZ;
#pragma unroll
            for (int r = 0; r < 4; r++) {
                int row = rloc + r;
                outt[(size_t)row * D_SZ + colg] = hval[r];
                if (t == T_LEN - 1)
                    out[(size_t)T_LEN * B_SZ * D_SZ + (size_t)(b * MR + row) * D_SZ + colg] = hval[r];
            }
        }
    }
}

// ---------------------------------------------------------------------------
extern "C" void kernel_launch(void* const* d_in, const int* in_sizes, int n_in,
                              void* d_out, int out_size, void* d_ws, size_t ws_size,
                              hipStream_t stream)
{
    const float* x   = (const float*)d_in[0];
    const float* Wih = (const float*)d_in[1];
    const float* Whh = (const float*)d_in[2];
    const float* bih = (const float*)d_in[3];
    const float* bhh = (const float*)d_in[4];
    float* out = (float*)d_out;

    char* ws = (char*)d_ws;
    float*        xp   = (float*)ws;                        // 512*64*1024*4 = 134217728 B
    unsigned int* hbuf = (unsigned int*)(ws + 134217728);   // 2*64*1024*4   = 524288 B
    int*          slot = (int*)(ws + 134217728 + 524288);   // 8*64 ints = 2048 B

    init_kernel<<<dim3(1), dim3(512), 0, stream>>>(slot);
    xproj_kernel<<<dim3(2048), dim3(256), 0, stream>>>(x, Wih, bih, xp);
    rnn_kernel<<<dim3(256), dim3(128), 0, stream>>>(xp, Whh, bhh, out, hbuf, slot);
}

// Round 8
// 2218.880 us; speedup vs baseline: 7.5219x; 1.5009x over previous
//
#include <hip/hip_runtime.h>
#include <hip/hip_bf16.h>

#define T_LEN 512
#define B_SZ  64
#define D_SZ  1024

typedef __attribute__((ext_vector_type(8))) short  short8;   // 8 bf16
typedef __attribute__((ext_vector_type(4))) float  f32x4;
typedef __attribute__((ext_vector_type(4))) unsigned short ushort4v;
typedef __attribute__((ext_vector_type(4))) unsigned int   uint4v;

__device__ __forceinline__ float bf2f(unsigned short u) {
    unsigned int x = ((unsigned int)u) << 16;
    return __uint_as_float(x);
}
__device__ __forceinline__ unsigned short f2bf(float f) {
    unsigned int x = __float_as_uint(f);
    unsigned int r = x + 0x7FFFu + ((x >> 16) & 1u);   // round-to-nearest-even
    return (unsigned short)(r >> 16);
}
// split via local temps (vector elements can't bind to references)
__device__ __forceinline__ void split2p(float f, unsigned short* hi, unsigned short* lo) {
    unsigned short h = f2bf(f);
    *hi = h;
    *lo = f2bf(f - bf2f(h));
}

// ---------------------------------------------------------------------------
// Sync layout: 8 teams x 64 ints (256 B) -> each team's 32 producer slots
// live in their own cacheline; no cross-team line sharing, no RMWs ever.
// ---------------------------------------------------------------------------
#define CNT_STRIDE 64

__global__ void init_kernel(int* slot) {
    int i = threadIdx.x;
    if (i < 8 * CNT_STRIDE) slot[i] = 0;
}

// ---------------------------------------------------------------------------
// Kernel B: xproj[t,b,:] = x[t,b,:] @ W_ih^T + b_ih   (fp32 out)
// Split-precision: A,B -> (hi,lo) bf16; acc += Ah*Bh + Al*Bh + Ah*Bl.
// M = T*B = 32768, N = D = 1024, K = D = 1024; 128x128 tile, BK=32, 4 waves.
// ---------------------------------------------------------------------------
#define BM 128
#define BN 128
#define BK 32
#define ASTR (BK + 8)   // 40 bf16 rows -> 80 B stride, spreads banks

__global__ __launch_bounds__(256) void xproj_kernel(
    const float* __restrict__ x, const float* __restrict__ Wih,
    const float* __restrict__ bih, float* __restrict__ xp)
{
    __shared__ unsigned short Ah[BM][ASTR];
    __shared__ unsigned short Al[BM][ASTR];
    __shared__ unsigned short Bh[BN][ASTR];
    __shared__ unsigned short Bl[BN][ASTR];

    const int nblk = D_SZ / BN;                 // 8
    const int bm = blockIdx.x / nblk;
    const int bn = blockIdx.x % nblk;
    const int m0 = bm * BM, n0 = bn * BN;
    const int tid  = threadIdx.x;
    const int lane = tid & 63, wave = tid >> 6;
    const int wm = wave >> 1, wn = wave & 1;

    f32x4 acc[4][4];
#pragma unroll
    for (int i = 0; i < 4; i++)
#pragma unroll
        for (int j = 0; j < 4; j++) acc[i][j] = (f32x4)0.0f;

    const int ar = lane & 15;
    const int kb = (lane >> 4) << 3;            // 0,8,16,24

    for (int k0 = 0; k0 < D_SZ; k0 += BK) {
#pragma unroll
        for (int i = 0; i < 4; i++) {
            int f4  = tid + i * 256;            // 0..1023
            int row = f4 >> 3;
            int c4  = (f4 & 7) << 2;
            f32x4 va = *reinterpret_cast<const f32x4*>(x   + (size_t)(m0 + row) * D_SZ + k0 + c4);
            f32x4 vb = *reinterpret_cast<const f32x4*>(Wih + (size_t)(n0 + row) * D_SZ + k0 + c4);
            ushort4v pah, pal, pbh, pbl;
#pragma unroll
            for (int e = 0; e < 4; e++) {
                unsigned short h_, l_;
                split2p(va[e], &h_, &l_); pah[e] = h_; pal[e] = l_;
                split2p(vb[e], &h_, &l_); pbh[e] = h_; pbl[e] = l_;
            }
            *reinterpret_cast<ushort4v*>(&Ah[row][c4]) = pah;
            *reinterpret_cast<ushort4v*>(&Al[row][c4]) = pal;
            *reinterpret_cast<ushort4v*>(&Bh[row][c4]) = pbh;
            *reinterpret_cast<ushort4v*>(&Bl[row][c4]) = pbl;
        }
        __syncthreads();

        short8 ah[4], al[4], bh[4], bl[4];
#pragma unroll
        for (int mi = 0; mi < 4; mi++) {
            ah[mi] = *reinterpret_cast<const short8*>(&Ah[wm * 64 + mi * 16 + ar][kb]);
            al[mi] = *reinterpret_cast<const short8*>(&Al[wm * 64 + mi * 16 + ar][kb]);
        }
#pragma unroll
        for (int ni = 0; ni < 4; ni++) {
            bh[ni] = *reinterpret_cast<const short8*>(&Bh[wn * 64 + ni * 16 + ar][kb]);
            bl[ni] = *reinterpret_cast<const short8*>(&Bl[wn * 64 + ni * 16 + ar][kb]);
        }
#pragma unroll
        for (int mi = 0; mi < 4; mi++)
#pragma unroll
            for (int ni = 0; ni < 4; ni++) {
                acc[mi][ni] = __builtin_amdgcn_mfma_f32_16x16x32_bf16(ah[mi], bh[ni], acc[mi][ni], 0, 0, 0);
                acc[mi][ni] = __builtin_amdgcn_mfma_f32_16x16x32_bf16(al[mi], bh[ni], acc[mi][ni], 0, 0, 0);
                acc[mi][ni] = __builtin_amdgcn_mfma_f32_16x16x32_bf16(ah[mi], bl[ni], acc[mi][ni], 0, 0, 0);
            }
        __syncthreads();
    }

    // epilogue: D row = (lane>>4)*4 + r, col = lane&15
    const int r0 = (lane >> 4) * 4;
    const int cl = lane & 15;
#pragma unroll
    for (int mi = 0; mi < 4; mi++) {
#pragma unroll
        for (int ni = 0; ni < 4; ni++) {
            int col = n0 + wn * 64 + ni * 16 + cl;
            float bias = bih[col];
            size_t base = (size_t)(m0 + wm * 64 + mi * 16 + r0) * D_SZ + col;
#pragma unroll
            for (int r = 0; r < 4; r++)
                xp[base + (size_t)r * D_SZ] = acc[mi][ni][r] + bias;
        }
    }
}

// ---------------------------------------------------------------------------
// Kernel C: persistent recurrence, split-precision.
// 256 wgs = 8 teams (8 batch rows, padded to 16) x 32 col groups (32 cols).
// W-hi in VGPRs (128), W-lo in LDS (frees the R7 VGPR-cap spills).
// h staged with 16 coherent dwordx4 loads (inline asm, sc0 sc1) issued
// back-to-back -> ONE MALL round trip (R7 had 4). Publish = slot-line store.
// ---------------------------------------------------------------------------
#define MR 8
#define NC 32
#define HSTR (D_SZ + 8)   // 1032: breaks power-of-2 bank stride, keeps 16B align

__global__ __launch_bounds__(128, 1) void rnn_kernel(
    const float* __restrict__ xp, const float* __restrict__ Whh,
    const float* __restrict__ bhh, float* __restrict__ out,
    unsigned int* hbuf, int* slot)
{
    __shared__ unsigned short Hh[16][HSTR];
    __shared__ unsigned short Hl[16][HSTR];
    __shared__ unsigned short Wlo[2][16][HSTR];   // per-wave 16-col W-lo plane

    const int wg = blockIdx.x;
    const int b  = wg & 7;      // team (batch group) -> same-XCD heuristic
    const int c  = wg >> 3;     // col group
    const int tid  = threadIdx.x;
    const int lane = tid & 63, wave = tid >> 6;

    const int cl   = lane & 15;
    const int hi4  = lane >> 4;             // 0..3
    const int kb   = hi4 << 3;              // k-chunk base within 32
    const int colg = c * NC + wave * 16 + cl;
    const float bias = bhh[colg];
    const int rloc = hi4 * 4;
    const bool active = (hi4 < 2);          // D rows 0..7 are real

    int* tslot = slot + b * CNT_STRIDE;     // this team's 32 publish slots

    // W_hh slice: hi plane -> registers (128 VGPR), lo plane -> LDS
    short8 wh[32];
    {
        const float* wrow = Whh + (size_t)colg * D_SZ;
#pragma unroll
        for (int kk = 0; kk < 32; kk++) {
            f32x4 v0 = *reinterpret_cast<const f32x4*>(wrow + kk * 32 + kb);
            f32x4 v1 = *reinterpret_cast<const f32x4*>(wrow + kk * 32 + kb + 4);
            short8 sh, sl;
#pragma unroll
            for (int e = 0; e < 4; e++) {
                unsigned short h_, l_;
                split2p(v0[e], &h_, &l_); sh[e] = (short)h_; sl[e] = (short)l_;
                split2p(v1[e], &h_, &l_); sh[4 + e] = (short)h_; sl[4 + e] = (short)l_;
            }
            wh[kk] = sh;
            *reinterpret_cast<short8*>(&Wlo[wave][cl][kk * 32 + kb]) = sl;
        }
    }
    // zero both H planes (h_0 = 0; rows 8..15 stay zero = M padding)
    for (int i = tid; i < 16 * HSTR; i += 128) {
        (&Hh[0][0])[i] = 0;
        (&Hl[0][0])[i] = 0;
    }
    __syncthreads();

    for (int t = 0; t < T_LEN; t++) {
        // ---- prefetch this step's xp values (independent of h) ----
        float xv[4];
        const float* xpt = xp + ((size_t)t * B_SZ + b * MR) * D_SZ;
        if (active) {
#pragma unroll
            for (int r = 0; r < 4; r++)
                xv[r] = xpt[(size_t)(rloc + r) * D_SZ + colg];
        }

        if (t > 0) {
            // wave 0 polls the team line: one coalesced 128B load + ballot
            if (wave == 0) {
                for (long it = 0; it < 200000000L; ++it) {
                    int v = __hip_atomic_load(tslot + (lane & 31), __ATOMIC_RELAXED, __HIP_MEMORY_SCOPE_AGENT);
                    if (__all(v >= t)) break;
                    __builtin_amdgcn_s_sleep(1);
                }
            }
            __syncthreads();
            // stage h: 8 rows x 1024 packed uints = 2048 uint4; 16 per thread.
            // All 16 coherent loads issued back-to-back -> one round trip.
            const uint4v* hsrc16 = reinterpret_cast<const uint4v*>(
                hbuf + ((size_t)(t & 1) * B_SZ + b * MR) * D_SZ);
            uint4v vv[16];
#pragma unroll
            for (int i = 0; i < 16; i++) {
                asm volatile("global_load_dwordx4 %0, %1, off sc0 sc1"
                             : "=v"(vv[i]) : "v"(hsrc16 + tid + i * 128) : "memory");
            }
            asm volatile("s_waitcnt vmcnt(8)" ::: "memory");
            __builtin_amdgcn_sched_barrier(0);
#pragma unroll
            for (int i = 0; i < 8; i++) {
                int j   = tid + i * 128;            // uint4 index, 0..2047
                int row = j >> 8;                   // 256 uint4 per row
                int c4  = (j & 255) << 2;           // ushort-pair col base
                ushort4v hh, hl;
#pragma unroll
                for (int e = 0; e < 4; e++) {
                    unsigned int u = vv[i][e];      // hi | lo<<16
                    hh[e] = (unsigned short)(u & 0xFFFFu);
                    hl[e] = (unsigned short)(u >> 16);
                }
                *reinterpret_cast<ushort4v*>(&Hh[row][c4]) = hh;
                *reinterpret_cast<ushort4v*>(&Hl[row][c4]) = hl;
            }
            asm volatile("s_waitcnt vmcnt(0)" ::: "memory");
            __builtin_amdgcn_sched_barrier(0);
#pragma unroll
            for (int i = 8; i < 16; i++) {
                int j   = tid + i * 128;
                int row = j >> 8;
                int c4  = (j & 255) << 2;
                ushort4v hh, hl;
#pragma unroll
                for (int e = 0; e < 4; e++) {
                    unsigned int u = vv[i][e];
                    hh[e] = (unsigned short)(u & 0xFFFFu);
                    hl[e] = (unsigned short)(u >> 16);
                }
                *reinterpret_cast<ushort4v*>(&Hh[row][c4]) = hh;
                *reinterpret_cast<ushort4v*>(&Hl[row][c4]) = hl;
            }
            __syncthreads();
        }

        // S[0:16][16 cols] = H @ Wslice^T, 3 independent chains
        f32x4 a0 = (f32x4)0.0f, a1 = (f32x4)0.0f, a2 = (f32x4)0.0f;
#pragma unroll
        for (int kk = 0; kk < 32; kk++) {
            short8 ah  = *reinterpret_cast<const short8*>(&Hh[cl][kk * 32 + kb]);
            short8 alo = *reinterpret_cast<const short8*>(&Hl[cl][kk * 32 + kb]);
            short8 wlv = *reinterpret_cast<const short8*>(&Wlo[wave][cl][kk * 32 + kb]);
            a0 = __builtin_amdgcn_mfma_f32_16x16x32_bf16(ah,  wh[kk], a0, 0, 0, 0);
            a1 = __builtin_amdgcn_mfma_f32_16x16x32_bf16(alo, wh[kk], a1, 0, 0, 0);
            a2 = __builtin_amdgcn_mfma_f32_16x16x32_bf16(ah,  wlv,    a2, 0, 0, 0);
        }

        float hval[4];
        if (active) {
            unsigned int* hdst = hbuf + ((size_t)((t + 1) & 1) * B_SZ + b * MR) * D_SZ;
#pragma unroll
            for (int r = 0; r < 4; r++) {
                int row = rloc + r;   // 0..7
                float pre = (a0[r] + a1[r] + a2[r]) + xv[r] + bias;
                float h = tanhf(pre);
                hval[r] = h;
                unsigned short hh_, ll_;
                split2p(h, &hh_, &ll_);
                unsigned int packed = (unsigned int)hh_ | ((unsigned int)ll_ << 16);
                __hip_atomic_store(&hdst[(size_t)row * D_SZ + colg], packed,
                                   __ATOMIC_RELAXED, __HIP_MEMORY_SCOPE_AGENT);
            }
        }
        // drain the sc1 h-stores to the coherence point, then publish.
        asm volatile("s_waitcnt vmcnt(0)" ::: "memory");
        __syncthreads();
        if (tid == 0)
            __hip_atomic_store(tslot + c, t + 1, __ATOMIC_RELAXED, __HIP_MEMORY_SCOPE_AGENT);

        // out stores AFTER publish: off the inter-team critical path
        if (active) {
            float* outt = out + ((size_t)t * B_SZ + b * MR) * D_SZ;
#pragma unroll
            for (int r = 0; r < 4; r++) {
                int row = rloc + r;
                outt[(size_t)row * D_SZ + colg] = hval[r];
                if (t == T_LEN - 1)
                    out[(size_t)T_LEN * B_SZ * D_SZ + (size_t)(b * MR + row) * D_SZ + colg] = hval[r];
            }
        }
    }
}

// ---------------------------------------------------------------------------
extern "C" void kernel_launch(void* const* d_in, const int* in_sizes, int n_in,
                              void* d_out, int out_size, void* d_ws, size_t ws_size,
                              hipStream_t stream)
{
    const float* x   = (const float*)d_in[0];
    const float* Wih = (const float*)d_in[1];
    const float* Whh = (const float*)d_in[2];
    const float* bih = (const float*)d_in[3];
    const float* bhh = (const float*)d_in[4];
    float* out = (float*)d_out;

    char* ws = (char*)d_ws;
    float*        xp   = (float*)ws;                        // 512*64*1024*4 = 134217728 B
    unsigned int* hbuf = (unsigned int*)(ws + 134217728);   // 2*64*1024*4   = 524288 B
    int*          slot = (int*)(ws + 134217728 + 524288);   // 8*64 ints = 2048 B

    init_kernel<<<dim3(1), dim3(512), 0, stream>>>(slot);
    xproj_kernel<<<dim3(2048), dim3(256), 0, stream>>>(x, Wih, bih, xp);
    rnn_kernel<<<dim3(256), dim3(128), 0, stream>>>(xp, Whh, bhh, out, hbuf, slot);
}